// Round 2
// baseline (154.966 us; speedup 1.0000x reference)
//
#include <hip/hip_runtime.h>
#include <math.h>

#define B 32
#define N 1024
#define W 128
#define R 4
#define EPSC 1e-8f

// ---- ws layout (in floats) ----
#define WS_SUM   0                              // 1 float (padded to 64)
#define WS_BW    64                             // B*16*R*N
#define WS_FW    (WS_BW + B*16*R*N)             // B*R*N
#define WS_CONT  (WS_FW + B*R*N)                // B*R*N
#define WS_COSR  (WS_CONT + B*R*N)              // B*R*N
#define WS_COSW  (WS_COSR + B*R*N)              // B*N
#define WS_WW    (WS_COSW + B*N)                // B*N

// ---- out offsets (in floats) ----
#define O_RR    0
#define O_MEM   (O_RR + B*R*W)
#define O_LINK  (O_MEM + B*N*W)
#define O_USAGE (O_LINK + B*N*N)
#define O_PREC  (O_USAGE + B*N)
#define O_NRW   (O_PREC + B*N)

// ===================== K1: cosine scores =====================
// grid B*64 (16 rows/block), block 256. 16 lanes per row -> 4-level reduce.
__global__ void k1_scores(const float* __restrict__ mem,
                          const float* __restrict__ rkeys,
                          const float* __restrict__ wkey,
                          float* __restrict__ ws) {
    int bx = blockIdx.x;
    int b = bx >> 6;
    int n0 = (bx & 63) << 4;
    int t = threadIdx.x;
    __shared__ float keys[5][W];
    __shared__ float knorm[5];
    for (int idx = t; idx < 5 * W; idx += 256) {
        int r = idx >> 7, w = idx & 127;
        keys[r][w] = (r < 4) ? rkeys[(b * R + r) * W + w] : wkey[b * W + w];
    }
    __syncthreads();
    if (t < 160) {
        int kidx = t >> 5, l = t & 31;
        float s = 0.f;
        #pragma unroll
        for (int c = 0; c < 4; ++c) { float v = keys[kidx][l * 4 + c]; s += v * v; }
        #pragma unroll
        for (int st = 1; st <= 16; st <<= 1) s += __shfl_xor(s, st);
        if (l == 0) knorm[kidx] = sqrtf(s);
    }
    __syncthreads();
    int l16 = t & 15;
    int rloc = t >> 4;          // 0..15
    int n = n0 + rloc;
    const float* mrow = mem + ((size_t)(b * N + n)) * W + l16 * 8;
    float4 a  = *reinterpret_cast<const float4*>(mrow);
    float4 a2 = *reinterpret_cast<const float4*>(mrow + 4);
    float mm = a.x*a.x + a.y*a.y + a.z*a.z + a.w*a.w
             + a2.x*a2.x + a2.y*a2.y + a2.z*a2.z + a2.w*a2.w;
    float d[5];
    #pragma unroll
    for (int r = 0; r < 5; ++r) {
        float4 k1v = *reinterpret_cast<const float4*>(&keys[r][l16 * 8]);
        float4 k2v = *reinterpret_cast<const float4*>(&keys[r][l16 * 8 + 4]);
        d[r] = a.x*k1v.x + a.y*k1v.y + a.z*k1v.z + a.w*k1v.w
             + a2.x*k2v.x + a2.y*k2v.y + a2.z*k2v.z + a2.w*k2v.w;
    }
    #pragma unroll
    for (int st = 1; st <= 8; st <<= 1) {
        mm += __shfl_xor(mm, st);
        #pragma unroll
        for (int r = 0; r < 5; ++r) d[r] += __shfl_xor(d[r], st);
    }
    if (l16 == 0) {
        float mn = sqrtf(mm);
        #pragma unroll
        for (int r = 0; r < 4; ++r)
            ws[WS_COSR + (b * R + r) * N + n] = d[r] / fmaxf(knorm[r] * mn, EPSC);
        ws[WS_COSW + b * N + n] = d[4] / fmaxf(knorm[4] * mn, EPSC);
    }
}

// ===================== K2: softmaxes + allocation + ww =====================
// grid B, block 1024 (one element per thread).
__global__ void k2_soft(const float* __restrict__ usage,
                        const float* __restrict__ rstr,
                        const float* __restrict__ wstr,
                        const float* __restrict__ agate,
                        const float* __restrict__ wgate,
                        float* __restrict__ ws) {
    int b = blockIdx.x, t = threadIdx.x;
    int lane = t & 63, wv = t >> 6;       // 16 waves
    __shared__ float red[16][8];
    __shared__ float fin[8];
    __shared__ float wsc[16];

    float x[5], m[5];
    #pragma unroll
    for (int r = 0; r < R; ++r) x[r] = ws[WS_COSR + (b * R + r) * N + t];
    x[4] = ws[WS_COSW + b * N + t] * wstr[b];
    #pragma unroll
    for (int q = 0; q < 5; ++q) m[q] = x[q];
    #pragma unroll
    for (int s = 1; s <= 32; s <<= 1) {
        #pragma unroll
        for (int q = 0; q < 5; ++q) m[q] = fmaxf(m[q], __shfl_xor(m[q], s));
    }
    if (lane == 0) { for (int q = 0; q < 5; ++q) red[wv][q] = m[q]; }
    __syncthreads();
    if (t < 80) {
        int q = t >> 4, w16 = t & 15;
        float v = red[w16][q];
        #pragma unroll
        for (int s = 1; s <= 8; s <<= 1) v = fmaxf(v, __shfl_xor(v, s));
        if (w16 == 0) fin[q] = v;
    }
    __syncthreads();
    float e[5], sm[5];
    #pragma unroll
    for (int q = 0; q < 5; ++q) { e[q] = expf(x[q] - fin[q]); sm[q] = e[q]; }
    #pragma unroll
    for (int s = 1; s <= 32; s <<= 1) {
        #pragma unroll
        for (int q = 0; q < 5; ++q) sm[q] += __shfl_xor(sm[q], s);
    }
    __syncthreads();   // red reuse hazard
    if (lane == 0) { for (int q = 0; q < 5; ++q) red[wv][q] = sm[q]; }
    __syncthreads();
    if (t < 80) {
        int q = t >> 4, w16 = t & 15;
        float v = red[w16][q];
        #pragma unroll
        for (int s = 1; s <= 8; s <<= 1) v += __shfl_xor(v, s);
        if (w16 == 0) fin[q] = v;
    }
    __syncthreads();
    #pragma unroll
    for (int r = 0; r < R; ++r)
        ws[WS_CONT + (b * R + r) * N + t] = e[r] / fin[r] * rstr[b * R + r];
    float wcv = e[4] / fin[4];

    // ---- exclusive cumprod scan of usage ----
    float u = usage[b * N + t];
    float incl = u;
    #pragma unroll
    for (int s = 1; s <= 32; s <<= 1) {
        float up = __shfl_up(incl, s);
        if (lane >= s) incl *= up;
    }
    if (lane == 63) wsc[wv] = incl;
    __syncthreads();
    if (t < 16) {
        float v = wsc[t];
        #pragma unroll
        for (int s = 1; s <= 8; s <<= 1) {
            float up = __shfl_up(v, s);
            if (lane >= s) v *= up;
        }
        wsc[t] = v;  // inclusive over waves
    }
    __syncthreads();
    float woff = (wv == 0) ? 1.f : wsc[wv - 1];
    float eu = __shfl_up(incl, 1);
    float excl = (lane == 0 ? 1.f : eu) * woff;
    float alloc = (1.f - u) * excl;

    float wwv = (agate[b] * (alloc - wcv) + wcv) * wgate[b];
    ws[WS_WW + b * N + t] = wwv;

    float s6 = wwv;
    #pragma unroll
    for (int s = 1; s <= 32; s <<= 1) s6 += __shfl_xor(s6, s);
    __syncthreads();
    if (lane == 0) red[wv][0] = s6;
    __syncthreads();
    if (t == 0) {
        float acc = 0.f;
        for (int w2 = 0; w2 < 16; ++w2) acc += red[w2][0];
        atomicAdd(&ws[WS_SUM], acc);
    }
}

// ===================== K3: single pass over L =====================
// grid B*16 (64-row strips), block 512. Thread: 2 fixed rows, 4 cols per 64x64 tile.
// fw register-accumulated (reduce once at end); bw: 2-level shfl pre-reduce + LDS atomics.
__global__ __launch_bounds__(512, 4) void k3_link(const float* __restrict__ L,
                        const float* __restrict__ rw,
                        const float* __restrict__ prec,
                        float* __restrict__ ws,
                        float* __restrict__ out) {
    int bx = blockIdx.x;
    int b = bx >> 4;
    int strip = bx & 15;
    int i0 = strip << 6;
    int t = threadIdx.x;
    int lane = t & 63;
    int t_lo = t & 15;
    int t_hi = t >> 4;          // 0..31
    __shared__ float ww_l[N];
    __shared__ float p_l[N];
    __shared__ float rw_l[R][N];
    __shared__ float bw_l[R][N];

    const float* wwg = ws + WS_WW + b * N;
    const float* pg  = prec + b * N;
    for (int idx = t; idx < N; idx += 512) {
        ww_l[idx] = wwg[idx];
        p_l[idx]  = pg[idx];
    }
    for (int idx = t; idx < R * N; idx += 512) {
        int r = idx >> 10, j = idx & 1023;
        rw_l[r][j] = rw[(b * R + r) * N + j];
        bw_l[r][j] = 0.f;
    }
    __syncthreads();

    int row0 = i0 + t_hi * 2;
    float wi0 = ww_l[row0], wi1 = ww_l[row0 + 1];
    float c00 = 1.f - wi0, c11 = 1.f - wi1;
    float rwi0[R], rwi1[R];
    #pragma unroll
    for (int r = 0; r < R; ++r) { rwi0[r] = rw_l[r][row0]; rwi1[r] = rw_l[r][row0 + 1]; }
    float fw0[R] = {0.f, 0.f, 0.f, 0.f};
    float fw1[R] = {0.f, 0.f, 0.f, 0.f};

    const float* Lr = L + ((size_t)(b * N + row0)) * N;
    float* Or = out + O_LINK + ((size_t)(b * N + row0)) * N;

    for (int tile = 0; tile < 16; ++tile) {
        int c0 = tile * 64 + t_lo * 4;
        float4 v0 = *reinterpret_cast<const float4*>(Lr + c0);
        float4 v1 = *reinterpret_cast<const float4*>(Lr + N + c0);
        float4 wwj = *reinterpret_cast<const float4*>(&ww_l[c0]);
        float4 pj  = *reinterpret_cast<const float4*>(&p_l[c0]);

        float4 o0, o1;
        o0.x = (c00 - wwj.x) * v0.x + wi0 * pj.x;
        o0.y = (c00 - wwj.y) * v0.y + wi0 * pj.y;
        o0.z = (c00 - wwj.z) * v0.z + wi0 * pj.z;
        o0.w = (c00 - wwj.w) * v0.w + wi0 * pj.w;
        o1.x = (c11 - wwj.x) * v1.x + wi1 * pj.x;
        o1.y = (c11 - wwj.y) * v1.y + wi1 * pj.y;
        o1.z = (c11 - wwj.z) * v1.z + wi1 * pj.z;
        o1.w = (c11 - wwj.w) * v1.w + wi1 * pj.w;
        *reinterpret_cast<float4*>(Or + c0) = o0;
        *reinterpret_cast<float4*>(Or + N + c0) = o1;

        float4 tmp[R];
        #pragma unroll
        for (int r = 0; r < R; ++r) {
            float4 rwj = *reinterpret_cast<const float4*>(&rw_l[r][c0]);
            fw0[r] += v0.x * rwj.x + v0.y * rwj.y + v0.z * rwj.z + v0.w * rwj.w;
            fw1[r] += v1.x * rwj.x + v1.y * rwj.y + v1.z * rwj.z + v1.w * rwj.w;
            tmp[r].x = rwi0[r] * v0.x + rwi1[r] * v1.x;
            tmp[r].y = rwi0[r] * v0.y + rwi1[r] * v1.y;
            tmp[r].z = rwi0[r] * v0.z + rwi1[r] * v1.z;
            tmp[r].w = rwi0[r] * v0.w + rwi1[r] * v1.w;
        }
        // pre-reduce over the wave's 4 row-groups (lane bits 4,5)
        #pragma unroll
        for (int r = 0; r < R; ++r) {
            tmp[r].x += __shfl_xor(tmp[r].x, 16); tmp[r].x += __shfl_xor(tmp[r].x, 32);
            tmp[r].y += __shfl_xor(tmp[r].y, 16); tmp[r].y += __shfl_xor(tmp[r].y, 32);
            tmp[r].z += __shfl_xor(tmp[r].z, 16); tmp[r].z += __shfl_xor(tmp[r].z, 32);
            tmp[r].w += __shfl_xor(tmp[r].w, 16); tmp[r].w += __shfl_xor(tmp[r].w, 32);
        }
        if ((lane & 48) == 0) {
            #pragma unroll
            for (int r = 0; r < R; ++r) {
                atomicAdd(&bw_l[r][c0 + 0], tmp[r].x);
                atomicAdd(&bw_l[r][c0 + 1], tmp[r].y);
                atomicAdd(&bw_l[r][c0 + 2], tmp[r].z);
                atomicAdd(&bw_l[r][c0 + 3], tmp[r].w);
            }
        }
    }
    __syncthreads();

    // bw: per-strip partials to ws (no global atomics)
    float* bwout = ws + WS_BW + (size_t)(b * 16 + strip) * R * N;
    {
        int flat = t * 8;
        int r = flat >> 10, j = flat & 1023;
        *reinterpret_cast<float4*>(bwout + r * N + j) =
            *reinterpret_cast<const float4*>(&bw_l[r][j]);
        *reinterpret_cast<float4*>(bwout + r * N + j + 4) =
            *reinterpret_cast<const float4*>(&bw_l[r][j + 4]);
    }

    // fw: reduce over t_lo (lane bits 0-3), then write final
    #pragma unroll
    for (int r = 0; r < R; ++r) {
        #pragma unroll
        for (int s = 1; s <= 8; s <<= 1) {
            fw0[r] += __shfl_xor(fw0[r], s);
            fw1[r] += __shfl_xor(fw1[r], s);
        }
    }
    if (t_lo == 0) {
        #pragma unroll
        for (int r = 0; r < R; ++r) {
            ws[WS_FW + (b * R + r) * N + row0]     = fw0[r];
            ws[WS_FW + (b * R + r) * N + row0 + 1] = fw1[r];
        }
    }
}

// ===================== K4: finalize =====================
// grid B*16 (64-row chunks), block 256.
__global__ void k4_final(const float* __restrict__ mem,
                         const float* __restrict__ usage,
                         const float* __restrict__ prec,
                         const float* __restrict__ rmodes,
                         const float* __restrict__ fgates,
                         const float* __restrict__ ev,
                         const float* __restrict__ wvec,
                         float* __restrict__ ws,
                         float* __restrict__ out) {
    int bx = blockIdx.x;
    int b = bx >> 4;
    int n0 = (bx & 15) << 6;
    int t = threadIdx.x;
    __shared__ float nrw[R][64];
    __shared__ float wwl[64];
    __shared__ float rrl[2][R][W];

    // phase 1: new_rw (256 = R*64 work items)
    {
        int r = t >> 6, nl = t & 63, n = n0 + nl;
        float bs = 0.f;
        #pragma unroll
        for (int tile = 0; tile < 16; ++tile)
            bs += ws[WS_BW + ((size_t)(b * 16 + tile) * R + r) * N + n];
        float fwv = ws[WS_FW + (b * R + r) * N + n];
        float cv  = ws[WS_CONT + (b * R + r) * N + n];
        float m0 = rmodes[(b * R + r) * 3 + 0];
        float m1 = rmodes[(b * R + r) * 3 + 1];
        float m2 = rmodes[(b * R + r) * 3 + 2];
        float v = fwv * m0 + bs * m1 + cv * m2;
        out[O_NRW + (b * R + r) * N + n] = v;
        nrw[r][nl] = v;
    }
    __syncthreads();

    // phase 2: usage_new, precedence_new
    if (t < 64) {
        int n = n0 + t;
        float ret = 1.f;
        #pragma unroll
        for (int r = 0; r < R; ++r) ret *= (1.f - fgates[b * R + r] * nrw[r][t]);
        float u = usage[b * N + n];
        float w = ws[WS_WW + b * N + n];
        out[O_USAGE + b * N + n] = (u + w - u * w) * ret;
        float S = ws[WS_SUM];
        out[O_PREC + b * N + n] = (1.f - S) * prec[b * N + n] + w;
        wwl[t] = w;
    }
    __syncthreads();

    // phase 3: memory_new + read_result partial
    int wi = t & 127, half = t >> 7;
    float er = ev[b * W + wi], wvv = wvec[b * W + wi];
    float acc[R] = {0.f, 0.f, 0.f, 0.f};
    for (int k = 0; k < 32; ++k) {
        int nl = half * 32 + k;
        int n = n0 + nl;
        size_t off = ((size_t)(b * N + n)) * W + wi;
        float m = mem[off];
        float wn = wwl[nl];
        out[O_MEM + off] = m * (1.f - wn * er) + wn * wvv;
        #pragma unroll
        for (int r = 0; r < R; ++r) acc[r] += nrw[r][nl] * m;
    }
    #pragma unroll
    for (int r = 0; r < R; ++r) rrl[half][r][wi] = acc[r];
    __syncthreads();
    for (int idx = t; idx < R * W; idx += 256) {
        int r = idx >> 7, w2 = idx & 127;
        atomicAdd(&out[O_RR + (b * R + r) * W + w2], rrl[0][r][w2] + rrl[1][r][w2]);
    }
}

extern "C" void kernel_launch(void* const* d_in, const int* in_sizes, int n_in,
                              void* d_out, int out_size, void* d_ws, size_t ws_size,
                              hipStream_t stream) {
    const float* mem    = (const float*)d_in[0];
    const float* L      = (const float*)d_in[1];
    const float* usage  = (const float*)d_in[2];
    const float* prec   = (const float*)d_in[3];
    const float* rw     = (const float*)d_in[4];
    const float* rkeys  = (const float*)d_in[5];
    const float* rstr   = (const float*)d_in[6];
    const float* rmodes = (const float*)d_in[7];
    const float* wkey   = (const float*)d_in[8];
    const float* wstr   = (const float*)d_in[9];
    const float* ag     = (const float*)d_in[10];
    const float* wg     = (const float*)d_in[11];
    const float* wv     = (const float*)d_in[12];
    const float* ev     = (const float*)d_in[13];
    const float* fg     = (const float*)d_in[14];
    float* out = (float*)d_out;
    float* ws  = (float*)d_ws;

    hipMemsetAsync(ws, 0, 256, stream);                                // sum_ww
    hipMemsetAsync(out, 0, (size_t)B * R * W * sizeof(float), stream); // read_result

    k1_scores<<<B * 64, 256, 0, stream>>>(mem, rkeys, wkey, ws);
    k2_soft<<<B, 1024, 0, stream>>>(usage, rstr, wstr, ag, wg, ws);
    k3_link<<<B * 16, 512, 0, stream>>>(L, rw, prec, ws, out);
    k4_final<<<B * 16, 256, 0, stream>>>(mem, usage, prec, rmodes, fg, ev, wv, ws, out);
}

// Round 4
// 78.339 us; speedup vs baseline: 1.9781x; 1.9781x over previous
//
#include <hip/hip_runtime.h>
#include <math.h>

#define B 32
#define N 1024
#define W 128
#define R 4
#define EPSC 1e-8f

typedef float f32x4 __attribute__((ext_vector_type(4)));

// ---- ws layout (in floats) ----
#define WS_SUM   0                              // 1 float (padded to 64)
#define WS_BW    64                             // B*16*R*N
#define WS_FW    (WS_BW + B*16*R*N)             // B*R*N
#define WS_CONT  (WS_FW + B*R*N)                // B*R*N
#define WS_COSR  (WS_CONT + B*R*N)              // B*R*N
#define WS_COSW  (WS_COSR + B*R*N)              // B*N
#define WS_WW    (WS_COSW + B*N)                // B*N

// ---- out offsets (in floats) ----
#define O_RR    0
#define O_MEM   (O_RR + B*R*W)
#define O_LINK  (O_MEM + B*N*W)
#define O_USAGE (O_LINK + B*N*N)
#define O_PREC  (O_USAGE + B*N)
#define O_NRW   (O_PREC + B*N)

// ===================== K1: cosine scores =====================
// grid B*64 (16 rows/block), block 256. 16 lanes per row -> 4-level reduce.
__global__ void k1_scores(const float* __restrict__ mem,
                          const float* __restrict__ rkeys,
                          const float* __restrict__ wkey,
                          float* __restrict__ ws) {
    int bx = blockIdx.x;
    int b = bx >> 6;
    int n0 = (bx & 63) << 4;
    int t = threadIdx.x;
    __shared__ float keys[5][W];
    __shared__ float knorm[5];
    for (int idx = t; idx < 5 * W; idx += 256) {
        int r = idx >> 7, w = idx & 127;
        keys[r][w] = (r < 4) ? rkeys[(b * R + r) * W + w] : wkey[b * W + w];
    }
    __syncthreads();
    if (t < 160) {
        int kidx = t >> 5, l = t & 31;
        float s = 0.f;
        #pragma unroll
        for (int c = 0; c < 4; ++c) { float v = keys[kidx][l * 4 + c]; s += v * v; }
        #pragma unroll
        for (int st = 1; st <= 16; st <<= 1) s += __shfl_xor(s, st);
        if (l == 0) knorm[kidx] = sqrtf(s);
    }
    __syncthreads();
    int l16 = t & 15;
    int rloc = t >> 4;          // 0..15
    int n = n0 + rloc;
    const float* mrow = mem + ((size_t)(b * N + n)) * W + l16 * 8;
    float4 a  = *reinterpret_cast<const float4*>(mrow);
    float4 a2 = *reinterpret_cast<const float4*>(mrow + 4);
    float mm = a.x*a.x + a.y*a.y + a.z*a.z + a.w*a.w
             + a2.x*a2.x + a2.y*a2.y + a2.z*a2.z + a2.w*a2.w;
    float d[5];
    #pragma unroll
    for (int r = 0; r < 5; ++r) {
        float4 k1v = *reinterpret_cast<const float4*>(&keys[r][l16 * 8]);
        float4 k2v = *reinterpret_cast<const float4*>(&keys[r][l16 * 8 + 4]);
        d[r] = a.x*k1v.x + a.y*k1v.y + a.z*k1v.z + a.w*k1v.w
             + a2.x*k2v.x + a2.y*k2v.y + a2.z*k2v.z + a2.w*k2v.w;
    }
    #pragma unroll
    for (int st = 1; st <= 8; st <<= 1) {
        mm += __shfl_xor(mm, st);
        #pragma unroll
        for (int r = 0; r < 5; ++r) d[r] += __shfl_xor(d[r], st);
    }
    if (l16 == 0) {
        float mn = sqrtf(mm);
        #pragma unroll
        for (int r = 0; r < 4; ++r)
            ws[WS_COSR + (b * R + r) * N + n] = d[r] / fmaxf(knorm[r] * mn, EPSC);
        ws[WS_COSW + b * N + n] = d[4] / fmaxf(knorm[4] * mn, EPSC);
    }
}

// ===================== K2: softmaxes + allocation + ww =====================
// grid B, block 1024 (one element per thread).
__global__ void k2_soft(const float* __restrict__ usage,
                        const float* __restrict__ rstr,
                        const float* __restrict__ wstr,
                        const float* __restrict__ agate,
                        const float* __restrict__ wgate,
                        float* __restrict__ ws) {
    int b = blockIdx.x, t = threadIdx.x;
    int lane = t & 63, wv = t >> 6;       // 16 waves
    __shared__ float red[16][8];
    __shared__ float fin[8];
    __shared__ float wsc[16];

    float x[5], m[5];
    #pragma unroll
    for (int r = 0; r < R; ++r) x[r] = ws[WS_COSR + (b * R + r) * N + t];
    x[4] = ws[WS_COSW + b * N + t] * wstr[b];
    #pragma unroll
    for (int q = 0; q < 5; ++q) m[q] = x[q];
    #pragma unroll
    for (int s = 1; s <= 32; s <<= 1) {
        #pragma unroll
        for (int q = 0; q < 5; ++q) m[q] = fmaxf(m[q], __shfl_xor(m[q], s));
    }
    if (lane == 0) { for (int q = 0; q < 5; ++q) red[wv][q] = m[q]; }
    __syncthreads();
    if (t < 80) {
        int q = t >> 4, w16 = t & 15;
        float v = red[w16][q];
        #pragma unroll
        for (int s = 1; s <= 8; s <<= 1) v = fmaxf(v, __shfl_xor(v, s));
        if (w16 == 0) fin[q] = v;
    }
    __syncthreads();
    float e[5], sm[5];
    #pragma unroll
    for (int q = 0; q < 5; ++q) { e[q] = expf(x[q] - fin[q]); sm[q] = e[q]; }
    #pragma unroll
    for (int s = 1; s <= 32; s <<= 1) {
        #pragma unroll
        for (int q = 0; q < 5; ++q) sm[q] += __shfl_xor(sm[q], s);
    }
    __syncthreads();   // red reuse hazard
    if (lane == 0) { for (int q = 0; q < 5; ++q) red[wv][q] = sm[q]; }
    __syncthreads();
    if (t < 80) {
        int q = t >> 4, w16 = t & 15;
        float v = red[w16][q];
        #pragma unroll
        for (int s = 1; s <= 8; s <<= 1) v += __shfl_xor(v, s);
        if (w16 == 0) fin[q] = v;
    }
    __syncthreads();
    #pragma unroll
    for (int r = 0; r < R; ++r)
        ws[WS_CONT + (b * R + r) * N + t] = e[r] / fin[r] * rstr[b * R + r];
    float wcv = e[4] / fin[4];

    // ---- exclusive cumprod scan of usage ----
    float u = usage[b * N + t];
    float incl = u;
    #pragma unroll
    for (int s = 1; s <= 32; s <<= 1) {
        float up = __shfl_up(incl, s);
        if (lane >= s) incl *= up;
    }
    if (lane == 63) wsc[wv] = incl;
    __syncthreads();
    if (t < 16) {
        float v = wsc[t];
        #pragma unroll
        for (int s = 1; s <= 8; s <<= 1) {
            float up = __shfl_up(v, s);
            if (lane >= s) v *= up;
        }
        wsc[t] = v;  // inclusive over waves
    }
    __syncthreads();
    float woff = (wv == 0) ? 1.f : wsc[wv - 1];
    float eu = __shfl_up(incl, 1);
    float excl = (lane == 0 ? 1.f : eu) * woff;
    float alloc = (1.f - u) * excl;

    float wwv = (agate[b] * (alloc - wcv) + wcv) * wgate[b];
    ws[WS_WW + b * N + t] = wwv;

    float s6 = wwv;
    #pragma unroll
    for (int s = 1; s <= 32; s <<= 1) s6 += __shfl_xor(s6, s);
    __syncthreads();
    if (lane == 0) red[wv][0] = s6;
    __syncthreads();
    if (t == 0) {
        float acc = 0.f;
        for (int w2 = 0; w2 < 16; ++w2) acc += red[w2][0];
        atomicAdd(&ws[WS_SUM], acc);
    }
}

// ===================== K3: single pass over L (v3) =====================
// grid B*16 (64-row strips), block 256. Thread owns 4 fixed cols.
// 8-row batched loads (MLP=8), bw register-accumulated, fw via LDS
// transpose-reduce (no per-row shuffle chains), NT stores for link_new.
__global__ void k3_link(const float* __restrict__ L,
                        const float* __restrict__ rw,
                        const float* __restrict__ prec,
                        float* __restrict__ ws,
                        float* __restrict__ out) {
    int bx = blockIdx.x;
    int b = bx >> 4;
    int strip = bx & 15;
    int i0 = strip << 6;
    int t = threadIdx.x;
    __shared__ float scratch[256][36];   // padded: float4-aligned, conflict-free
    __shared__ float ww_row[64];
    __shared__ float rw_row[R][64];

    if (t < 64) ww_row[t] = ws[WS_WW + b * N + i0 + t];
    for (int idx = t; idx < R * 64; idx += 256) {
        int r = idx >> 6, i = idx & 63;
        rw_row[r][i] = rw[(b * R + r) * N + i0 + i];
    }
    __syncthreads();

    int j0 = 4 * t;
    float4 wwj = *reinterpret_cast<const float4*>(ws + WS_WW + b * N + j0);
    float4 pj  = *reinterpret_cast<const float4*>(prec + b * N + j0);
    float4 rwj[R];
    #pragma unroll
    for (int r = 0; r < R; ++r)
        rwj[r] = *reinterpret_cast<const float4*>(rw + (b * R + r) * N + j0);
    float4 bwa[R];
    #pragma unroll
    for (int r = 0; r < R; ++r) bwa[r] = make_float4(0.f, 0.f, 0.f, 0.f);

    const float* Lr = L + ((size_t)(b * N + i0)) * N + j0;
    float* Or = out + O_LINK + ((size_t)(b * N + i0)) * N + j0;

    int g = t >> 3, kk = t & 7;   // reduce-phase role: output g, reducer kk

    for (int batch = 0; batch < 8; ++batch) {
        // --- issue 8 independent loads ---
        float4 v[8];
        #pragma unroll
        for (int k = 0; k < 8; ++k)
            v[k] = *reinterpret_cast<const float4*>(Lr + (size_t)(batch * 8 + k) * N);

        float4 fwp[8];
        #pragma unroll
        for (int k = 0; k < 8; ++k) {
            int row = batch * 8 + k;
            float wi = ww_row[row];
            float c = 1.f - wi;
            f32x4 o;
            o.x = (c - wwj.x) * v[k].x + wi * pj.x;
            o.y = (c - wwj.y) * v[k].y + wi * pj.y;
            o.z = (c - wwj.z) * v[k].z + wi * pj.z;
            o.w = (c - wwj.w) * v[k].w + wi * pj.w;
            __builtin_nontemporal_store(o,
                reinterpret_cast<f32x4*>(Or + (size_t)row * N));
            float4 f;
            f.x = v[k].x*rwj[0].x + v[k].y*rwj[0].y + v[k].z*rwj[0].z + v[k].w*rwj[0].w;
            f.y = v[k].x*rwj[1].x + v[k].y*rwj[1].y + v[k].z*rwj[1].z + v[k].w*rwj[1].w;
            f.z = v[k].x*rwj[2].x + v[k].y*rwj[2].y + v[k].z*rwj[2].z + v[k].w*rwj[2].w;
            f.w = v[k].x*rwj[3].x + v[k].y*rwj[3].y + v[k].z*rwj[3].z + v[k].w*rwj[3].w;
            fwp[k] = f;
            #pragma unroll
            for (int r = 0; r < R; ++r) {
                float q = rw_row[r][row];
                bwa[r].x += q * v[k].x; bwa[r].y += q * v[k].y;
                bwa[r].z += q * v[k].z; bwa[r].w += q * v[k].w;
            }
        }

        // --- fw transpose-reduce: scratch[t][row_k*4 + r] = partial ---
        #pragma unroll
        for (int k = 0; k < 8; ++k)
            *reinterpret_cast<float4*>(&scratch[t][k * 4]) = fwp[k];
        __syncthreads();
        float s = 0.f;
        #pragma unroll
        for (int m = 0; m < 32; ++m) s += scratch[kk + 8 * m][g];
        s += __shfl_xor(s, 1);
        s += __shfl_xor(s, 2);
        s += __shfl_xor(s, 4);
        if (kk == 0) {
            int rowk = g >> 2, r = g & 3;
            ws[WS_FW + (b * R + r) * N + i0 + batch * 8 + rowk] = s;
        }
        __syncthreads();
    }

    // bw: per-strip partials to ws (no global atomics)
    float* bwout = ws + WS_BW + (size_t)(b * 16 + strip) * R * N;
    #pragma unroll
    for (int r = 0; r < R; ++r)
        *reinterpret_cast<float4*>(bwout + r * N + j0) = bwa[r];
}

// ===================== K4: finalize =====================
// grid B*16 (64-row chunks), block 256.
__global__ void k4_final(const float* __restrict__ mem,
                         const float* __restrict__ usage,
                         const float* __restrict__ prec,
                         const float* __restrict__ rmodes,
                         const float* __restrict__ fgates,
                         const float* __restrict__ ev,
                         const float* __restrict__ wvec,
                         float* __restrict__ ws,
                         float* __restrict__ out) {
    int bx = blockIdx.x;
    int b = bx >> 4;
    int n0 = (bx & 15) << 6;
    int t = threadIdx.x;
    __shared__ float nrw[R][64];
    __shared__ float wwl[64];
    __shared__ float rrl[2][R][W];

    // phase 1: new_rw (256 = R*64 work items)
    {
        int r = t >> 6, nl = t & 63, n = n0 + nl;
        float bs = 0.f;
        #pragma unroll
        for (int tile = 0; tile < 16; ++tile)
            bs += ws[WS_BW + ((size_t)(b * 16 + tile) * R + r) * N + n];
        float fwv = ws[WS_FW + (b * R + r) * N + n];
        float cv  = ws[WS_CONT + (b * R + r) * N + n];
        float m0 = rmodes[(b * R + r) * 3 + 0];
        float m1 = rmodes[(b * R + r) * 3 + 1];
        float m2 = rmodes[(b * R + r) * 3 + 2];
        float v = fwv * m0 + bs * m1 + cv * m2;
        out[O_NRW + (b * R + r) * N + n] = v;
        nrw[r][nl] = v;
    }
    __syncthreads();

    // phase 2: usage_new, precedence_new
    if (t < 64) {
        int n = n0 + t;
        float ret = 1.f;
        #pragma unroll
        for (int r = 0; r < R; ++r) ret *= (1.f - fgates[b * R + r] * nrw[r][t]);
        float u = usage[b * N + n];
        float w = ws[WS_WW + b * N + n];
        out[O_USAGE + b * N + n] = (u + w - u * w) * ret;
        float S = ws[WS_SUM];
        out[O_PREC + b * N + n] = (1.f - S) * prec[b * N + n] + w;
        wwl[t] = w;
    }
    __syncthreads();

    // phase 3: memory_new + read_result partial
    int wi = t & 127, half = t >> 7;
    float er = ev[b * W + wi], wvv = wvec[b * W + wi];
    float acc[R] = {0.f, 0.f, 0.f, 0.f};
    for (int k = 0; k < 32; ++k) {
        int nl = half * 32 + k;
        int n = n0 + nl;
        size_t off = ((size_t)(b * N + n)) * W + wi;
        float m = mem[off];
        float wn = wwl[nl];
        out[O_MEM + off] = m * (1.f - wn * er) + wn * wvv;
        #pragma unroll
        for (int r = 0; r < R; ++r) acc[r] += nrw[r][nl] * m;
    }
    #pragma unroll
    for (int r = 0; r < R; ++r) rrl[half][r][wi] = acc[r];
    __syncthreads();
    for (int idx = t; idx < R * W; idx += 256) {
        int r = idx >> 7, w2 = idx & 127;
        atomicAdd(&out[O_RR + (b * R + r) * W + w2], rrl[0][r][w2] + rrl[1][r][w2]);
    }
}

extern "C" void kernel_launch(void* const* d_in, const int* in_sizes, int n_in,
                              void* d_out, int out_size, void* d_ws, size_t ws_size,
                              hipStream_t stream) {
    const float* mem    = (const float*)d_in[0];
    const float* L      = (const float*)d_in[1];
    const float* usage  = (const float*)d_in[2];
    const float* prec   = (const float*)d_in[3];
    const float* rw     = (const float*)d_in[4];
    const float* rkeys  = (const float*)d_in[5];
    const float* rstr   = (const float*)d_in[6];
    const float* rmodes = (const float*)d_in[7];
    const float* wkey   = (const float*)d_in[8];
    const float* wstr   = (const float*)d_in[9];
    const float* ag     = (const float*)d_in[10];
    const float* wg     = (const float*)d_in[11];
    const float* wv     = (const float*)d_in[12];
    const float* ev     = (const float*)d_in[13];
    const float* fg     = (const float*)d_in[14];
    float* out = (float*)d_out;
    float* ws  = (float*)d_ws;

    (void)hipMemsetAsync(ws, 0, 256, stream);                                // sum_ww
    (void)hipMemsetAsync(out, 0, (size_t)B * R * W * sizeof(float), stream); // read_result

    k1_scores<<<B * 64, 256, 0, stream>>>(mem, rkeys, wkey, ws);
    k2_soft<<<B, 1024, 0, stream>>>(usage, rstr, wstr, ag, wg, ws);
    k3_link<<<B * 16, 256, 0, stream>>>(L, rw, prec, ws, out);
    k4_final<<<B * 16, 256, 0, stream>>>(mem, usage, prec, rmodes, fg, ev, wv, ws, out);
}